// Round 6
// baseline (333.151 us; speedup 1.0000x reference)
//
#include <hip/hip_runtime.h>
#include <hip/hip_fp16.h>

// GCN encoder on MI355X. CSR (counting sort by dst) + XCD-channel-sliced gather
// aggregation: block's slice id = blockIdx & (S-1), so each XCD (blockIdx % 8
// round-robin) touches only one channel slice of the gathered activation array
// -> slice fits the 4 MiB per-XCD L2 -> random row re-reads become L2 hits.
// fp16 activations, fp32 agg buffers, no atomics in agg path. MFMA layer-1 GEMM.

#define K_DIM 128

typedef _Float16 f16x8 __attribute__((ext_vector_type(8)));
typedef _Float16 f16x4 __attribute__((ext_vector_type(4)));
typedef float f32x4 __attribute__((ext_vector_type(4)));

// ---------- CSR build ----------
__global__ __launch_bounds__(256) void hist_kernel(const int* __restrict__ dst,
                                                   int* counts, int E) {
    int i = blockIdx.x * 256 + threadIdx.x;
    if (i < E) atomicAdd(&counts[dst[i]], 1);
}

__global__ __launch_bounds__(256) void scan_block_kernel(const int* __restrict__ counts,
                                                         int* row_ptr, int* partials,
                                                         float* dinv, int N) {
    __shared__ int sm[256];
    int t = threadIdx.x;
    int i = blockIdx.x * 256 + t;
    int v = (i < N) ? counts[i] : 0;
    if (i < N) dinv[i] = rsqrtf((float)(v + 1));
    sm[t] = v;
    __syncthreads();
    for (int off = 1; off < 256; off <<= 1) {
        int add = (t >= off) ? sm[t - off] : 0;
        __syncthreads();
        sm[t] += add;
        __syncthreads();
    }
    if (i < N) row_ptr[i] = sm[t] - v;  // block-local exclusive
    if (t == 255) partials[blockIdx.x] = sm[255];
}

__global__ __launch_bounds__(256) void scan_partials_kernel(int* partials, int NB) {
    __shared__ int sm[256];
    int t = threadIdx.x;
    int v = (t < NB) ? partials[t] : 0;
    sm[t] = v;
    __syncthreads();
    for (int off = 1; off < 256; off <<= 1) {
        int add = (t >= off) ? sm[t - off] : 0;
        __syncthreads();
        sm[t] += add;
        __syncthreads();
    }
    if (t < NB) partials[t] = sm[t] - v;  // exclusive
}

__global__ __launch_bounds__(256) void fill_kernel(const int* __restrict__ src,
                                                   const int* __restrict__ dst,
                                                   const float* __restrict__ dinv,
                                                   int* row_ptr,
                                                   const int* __restrict__ partials,
                                                   int2* edges, int E) {
    int i = blockIdx.x * 256 + threadIdx.x;
    if (i < E) {
        int d = dst[i];
        int s = src[i];
        int pos = atomicAdd(&row_ptr[d], 1) + partials[d >> 8];
        edges[pos] = make_int2(s, __float_as_int(dinv[s] * dinv[d]));
    }
}

// ---------- W1 -> W1^T fp16 ----------
__global__ __launch_bounds__(256) void wt_prep_kernel(const float* __restrict__ W1,
                                                      _Float16* __restrict__ WT) {
    int idx = blockIdx.x * 256 + threadIdx.x;
    if (idx < 128 * 128) {
        int k = idx >> 7, j = idx & 127;
        WT[j * 128 + k] = (_Float16)W1[idx];
    }
}

// ---------- GEMM1 (MFMA): h1 = X @ W1, f16 out ----------
__global__ __launch_bounds__(256) void gemm1_mfma_kernel(const float* __restrict__ X,
                                                         const _Float16* __restrict__ WT,
                                                         __half* __restrict__ H, int N) {
    __shared__ _Float16 As[64][136];

    int row0 = blockIdx.x * 64;
    {
        int r = threadIdx.x >> 2;
        int c0 = (threadIdx.x & 3) * 32;
        int row = row0 + r;
        if (row < N) {
            const float4* srcp = (const float4*)(X + (size_t)row * 128 + c0);
#pragma unroll
            for (int i = 0; i < 8; ++i) {
                float4 v = srcp[i];
                f16x4 h = {(_Float16)v.x, (_Float16)v.y, (_Float16)v.z, (_Float16)v.w};
                *(f16x4*)&As[r][c0 + 4 * i] = h;
            }
        } else {
            f16x4 z = {};
#pragma unroll
            for (int i = 0; i < 8; ++i) *(f16x4*)&As[r][c0 + 4 * i] = z;
        }
    }
    __syncthreads();

    int wave = threadIdx.x >> 6;
    int lane = threadIdx.x & 63;
    int l15 = lane & 15;
    int k0 = (lane >> 4) * 8;
    int arow = wave * 16 + l15;

    f32x4 acc[8] = {};
#pragma unroll
    for (int ks = 0; ks < 4; ++ks) {
        f16x8 a = *(const f16x8*)&As[arow][ks * 32 + k0];
#pragma unroll
        for (int t = 0; t < 8; ++t) {
            f16x8 b = *(const f16x8*)(WT + (size_t)(t * 16 + l15) * 128 + ks * 32 + k0);
            acc[t] = __builtin_amdgcn_mfma_f32_16x16x32_f16(a, b, acc[t], 0, 0, 0);
        }
    }

    int rbase = row0 + wave * 16 + (lane >> 4) * 4;
#pragma unroll
    for (int t = 0; t < 8; ++t) {
#pragma unroll
        for (int r = 0; r < 4; ++r) {
            int row = rbase + r;
            if (row < N) H[(size_t)row * 128 + t * 16 + l15] = __float2half(acc[t][r]);
        }
    }
}

// ---------- agg1 sliced: agg1[n][128] = sum_e w * h1[src][128], slice of 32 ch ----------
// grid = ceil(N/4) * 4 slices; slice = blockIdx & 3 (maps to fixed XCD set).
// Wave = one (node, slice): lane = sub(4) x chpair(16). 4 edges / iter, x4 unroll.
__global__ __launch_bounds__(256) void agg1_sliced_kernel(
    const __half* __restrict__ h1, const float* __restrict__ dinv,
    const int* __restrict__ row_ptr, const int* __restrict__ counts,
    const int* __restrict__ partials, const int2* __restrict__ edges,
    float* __restrict__ agg1, int N) {
    int slice = blockIdx.x & 3;
    int wave = threadIdx.x >> 6;
    int node = (blockIdx.x >> 2) * 4 + wave;
    if (node >= N) return;
    int lane = threadIdx.x & 63;
    int sub = lane >> 4;        // 0..3: which edge of the group
    int cp = lane & 15;         // ch pair within slice

    const __half2* h2 = (const __half2*)h1;   // row stride 64 half2
    int coff = slice * 16 + cp;               // half2 offset within row

    float2 acc = make_float2(0.0f, 0.0f);
    if (sub == 0) {
        float dd = dinv[node];
        float2 f = __half22float2(h2[(size_t)node * 64 + coff]);
        acc.x = f.x * dd * dd;
        acc.y = f.y * dd * dd;
    }

    int end = row_ptr[node] + partials[node >> 8];
    int beg = end - counts[node];
    for (int e = beg; e < end; e += 16) {
        long long rec[4];
#pragma unroll
        for (int u = 0; u < 4; ++u) {
            int idx = e + 4 * u + sub;
            int cidx = idx < end ? idx : end - 1;
            rec[u] = __builtin_nontemporal_load((const long long*)&edges[cidx]);
            if (idx >= end) rec[u] &= 0xFFFFFFFFLL;  // zero weight for tail
        }
        __half2 v[4];
#pragma unroll
        for (int u = 0; u < 4; ++u)
            v[u] = h2[(size_t)(int)rec[u] * 64 + coff];
#pragma unroll
        for (int u = 0; u < 4; ++u) {
            float w = __int_as_float((int)(rec[u] >> 32));
            float2 f = __half22float2(v[u]);
            acc.x = fmaf(f.x, w, acc.x);
            acc.y = fmaf(f.y, w, acc.y);
        }
    }

    // combine the 4 edge-subgroups
    acc.x += __shfl_xor(acc.x, 16);
    acc.y += __shfl_xor(acc.y, 16);
    acc.x += __shfl_xor(acc.x, 32);
    acc.y += __shfl_xor(acc.y, 32);
    if (sub == 0)
        ((float2*)(agg1 + (size_t)node * 128 + slice * 32))[cp] = acc;
}

// ---------- ln1 + ReLU + W2 matvec: agg1 -> h3 (fp16) ----------
__global__ __launch_bounds__(256) void ln1_w2_kernel(
    const float* __restrict__ agg1, const float* __restrict__ b1,
    const float* __restrict__ g1, const float* __restrict__ beta1,
    const float* __restrict__ W2, __half* __restrict__ h3, int N) {
    __shared__ float lds[4][K_DIM];
    int wave = threadIdx.x >> 6;
    int lane = threadIdx.x & 63;
    int node = blockIdx.x * 4 + wave;
    if (node >= N) return;

    float2 a = ((const float2*)(agg1 + (size_t)node * 128))[lane];
    float2 bb = ((const float2*)b1)[lane];
    a.x += bb.x; a.y += bb.y;
    float s = a.x + a.y;
    for (int off = 32; off; off >>= 1) s += __shfl_xor(s, off);
    float mu = s * (1.0f / 128.0f);
    float dx = a.x - mu, dy = a.y - mu;
    float q = dx * dx + dy * dy;
    for (int off = 32; off; off >>= 1) q += __shfl_xor(q, off);
    float rstd = rsqrtf(q * (1.0f / 128.0f) + 1e-5f);
    float2 gg = ((const float2*)g1)[lane];
    float2 be = ((const float2*)beta1)[lane];
    float ox = fmaxf(fmaf(dx * rstd, gg.x, be.x), 0.0f);
    float oy = fmaxf(fmaf(dy * rstd, gg.y, be.y), 0.0f);

    ((float2*)&lds[wave][0])[lane] = make_float2(ox, oy);
    float o = 0.0f;
#pragma unroll 8
    for (int k = 0; k < K_DIM; k += 4) {
        float4 vv = *(const float4*)&lds[wave][k];
        o = fmaf(vv.x, W2[(size_t)(k + 0) * 64 + lane], o);
        o = fmaf(vv.y, W2[(size_t)(k + 1) * 64 + lane], o);
        o = fmaf(vv.z, W2[(size_t)(k + 2) * 64 + lane], o);
        o = fmaf(vv.w, W2[(size_t)(k + 3) * 64 + lane], o);
    }
    h3[(size_t)node * 64 + lane] = __float2half(o);
}

// ---------- agg2 sliced: agg2[n][64] from h3, slice of 32 ch, S=2 ----------
__global__ __launch_bounds__(256) void agg2_sliced_kernel(
    const __half* __restrict__ h3, const float* __restrict__ dinv,
    const int* __restrict__ row_ptr, const int* __restrict__ counts,
    const int* __restrict__ partials, const int2* __restrict__ edges,
    float* __restrict__ agg2, int N) {
    int slice = blockIdx.x & 1;
    int wave = threadIdx.x >> 6;
    int node = (blockIdx.x >> 1) * 4 + wave;
    if (node >= N) return;
    int lane = threadIdx.x & 63;
    int sub = lane >> 4;
    int cp = lane & 15;

    const __half2* h2 = (const __half2*)h3;   // row stride 32 half2
    int coff = slice * 16 + cp;

    float2 acc = make_float2(0.0f, 0.0f);
    if (sub == 0) {
        float dd = dinv[node];
        float2 f = __half22float2(h2[(size_t)node * 32 + coff]);
        acc.x = f.x * dd * dd;
        acc.y = f.y * dd * dd;
    }

    int end = row_ptr[node] + partials[node >> 8];
    int beg = end - counts[node];
    for (int e = beg; e < end; e += 16) {
        long long rec[4];
#pragma unroll
        for (int u = 0; u < 4; ++u) {
            int idx = e + 4 * u + sub;
            int cidx = idx < end ? idx : end - 1;
            rec[u] = __builtin_nontemporal_load((const long long*)&edges[cidx]);
            if (idx >= end) rec[u] &= 0xFFFFFFFFLL;
        }
        __half2 v[4];
#pragma unroll
        for (int u = 0; u < 4; ++u)
            v[u] = h2[(size_t)(int)rec[u] * 32 + coff];
#pragma unroll
        for (int u = 0; u < 4; ++u) {
            float w = __int_as_float((int)(rec[u] >> 32));
            float2 f = __half22float2(v[u]);
            acc.x = fmaf(f.x, w, acc.x);
            acc.y = fmaf(f.y, w, acc.y);
        }
    }

    acc.x += __shfl_xor(acc.x, 16);
    acc.y += __shfl_xor(acc.y, 16);
    acc.x += __shfl_xor(acc.x, 32);
    acc.y += __shfl_xor(acc.y, 32);
    if (sub == 0)
        ((float2*)(agg2 + (size_t)node * 64 + slice * 32))[cp] = acc;
}

// ---------- ln2 + ReLU + L2 normalize: agg2 -> out ----------
__global__ __launch_bounds__(256) void ln2_l2_kernel(
    const float* __restrict__ agg2, const float* __restrict__ b2,
    const float* __restrict__ g2, const float* __restrict__ beta2,
    float* __restrict__ out, int N) {
    int wave = threadIdx.x >> 6;
    int lane = threadIdx.x & 63;
    int node = blockIdx.x * 4 + wave;
    if (node >= N) return;

    float v = agg2[(size_t)node * 64 + lane] + b2[lane];
    float s = v;
    for (int off = 32; off; off >>= 1) s += __shfl_xor(s, off);
    float mu = s * (1.0f / 64.0f);
    float d = v - mu;
    float q = d * d;
    for (int off = 32; off; off >>= 1) q += __shfl_xor(q, off);
    float rstd = rsqrtf(q * (1.0f / 64.0f) + 1e-5f);
    float o = fmaxf(fmaf(d * rstd, g2[lane], beta2[lane]), 0.0f);
    float q2 = o * o;
    for (int off = 32; off; off >>= 1) q2 += __shfl_xor(q2, off);
    float nrm = sqrtf(q2);
    out[(size_t)node * 64 + lane] = o / fmaxf(nrm, 1e-12f);
}

extern "C" void kernel_launch(void* const* d_in, const int* in_sizes, int n_in,
                              void* d_out, int out_size, void* d_ws, size_t ws_size,
                              hipStream_t stream) {
    const float* x     = (const float*)d_in[0];
    const int*   ei    = (const int*)d_in[1];
    const float* W1    = (const float*)d_in[2];
    const float* b1    = (const float*)d_in[3];
    const float* g1    = (const float*)d_in[4];
    const float* beta1 = (const float*)d_in[5];
    const float* W2    = (const float*)d_in[6];
    const float* b2    = (const float*)d_in[7];
    const float* g2    = (const float*)d_in[8];
    const float* beta2 = (const float*)d_in[9];

    const int N = in_sizes[0] / 128;
    const int E = in_sizes[1] / 2;
    const int* src = ei;       // edge_index[0]
    const int* dst = ei + E;   // edge_index[1]
    float* out = (float*)d_out;

    // Workspace (~52 MB): agg2 aliases h1 (h1 dead after agg1_sliced).
    char* p = (char*)d_ws;
    auto alloc = [&](size_t bytes) { char* r = p; p += (bytes + 255) & ~(size_t)255; return r; };
    int*      counts   = (int*)alloc((size_t)N * 4);
    int*      row_ptr  = (int*)alloc((size_t)N * 4);
    int*      partials = (int*)alloc(256 * 4);
    float*    dinv     = (float*)alloc((size_t)N * 4);
    int2*     edges    = (int2*)alloc((size_t)E * 8);
    _Float16* WT       = (_Float16*)alloc(128 * 128 * 2);
    __half*   h1       = (__half*)alloc((size_t)N * 128 * 2);   // 12.8 MB
    float*    agg1     = (float*)alloc((size_t)N * 128 * 4);    // 25.6 MB
    __half*   h3       = (__half*)alloc((size_t)N * 64 * 2);    // 6.4 MB
    float*    agg2     = (float*)h1;                            // alias (12.8 MB)

    const int nb_nodes = (N + 255) / 256;
    const int nb_edges = (E + 255) / 256;
    const int nb_wave_nodes = (N + 3) / 4;

    // CSR build + dinv + packed edge records
    hipMemsetAsync(counts, 0, (size_t)N * 4, stream);
    hist_kernel<<<nb_edges, 256, 0, stream>>>(dst, counts, E);
    scan_block_kernel<<<nb_nodes, 256, 0, stream>>>(counts, row_ptr, partials, dinv, N);
    scan_partials_kernel<<<1, 256, 0, stream>>>(partials, nb_nodes);
    fill_kernel<<<nb_edges, 256, 0, stream>>>(src, dst, dinv, row_ptr, partials, edges, E);

    // layer 1 GEMM (MFMA, f16 out)
    wt_prep_kernel<<<64, 256, 0, stream>>>(W1, WT);
    gemm1_mfma_kernel<<<(N + 63) / 64, 256, 0, stream>>>(x, WT, h1, N);

    // layer 1 aggregate (XCD-sliced, S=4) then LN+ReLU+W2
    agg1_sliced_kernel<<<nb_wave_nodes * 4, 256, 0, stream>>>(
        h1, dinv, row_ptr, counts, partials, edges, agg1, N);
    ln1_w2_kernel<<<nb_wave_nodes, 256, 0, stream>>>(agg1, b1, g1, beta1, W2, h3, N);

    // layer 2 aggregate (XCD-sliced, S=2) then LN+ReLU+L2
    agg2_sliced_kernel<<<nb_wave_nodes * 2, 256, 0, stream>>>(
        h3, dinv, row_ptr, counts, partials, edges, agg2, N);
    ln2_l2_kernel<<<nb_wave_nodes, 256, 0, stream>>>(agg2, b2, g2, beta2, out, N);
}

// Round 7
// 212.298 us; speedup vs baseline: 1.5693x; 1.5693x over previous
//
#include <hip/hip_runtime.h>
#include <hip/hip_fp16.h>

// GCN encoder on MI355X. CSR (counting sort by dst) + fused gather aggregation.
// fp16 activations; 4-byte edge records {w:fp16 | src:u16} (requires N < 65536,
// problem is N=50000); wave-uniform record loads (scalar path); predicated
// unroll-8 gather; MFMA layer-1 GEMM; LN/ReLU/W2/L2 epilogues fused.

#define K_DIM 128

typedef _Float16 f16x8 __attribute__((ext_vector_type(8)));
typedef _Float16 f16x4 __attribute__((ext_vector_type(4)));
typedef float f32x4 __attribute__((ext_vector_type(4)));

// ---------- CSR build ----------
__global__ __launch_bounds__(256) void hist_kernel(const int* __restrict__ dst,
                                                   int* counts, int E) {
    int i = blockIdx.x * 256 + threadIdx.x;
    if (i < E) atomicAdd(&counts[dst[i]], 1);
}

__global__ __launch_bounds__(256) void scan_block_kernel(const int* __restrict__ counts,
                                                         int* row_ptr, int* partials,
                                                         float* dinv, int N) {
    __shared__ int sm[256];
    int t = threadIdx.x;
    int i = blockIdx.x * 256 + t;
    int v = (i < N) ? counts[i] : 0;
    if (i < N) dinv[i] = rsqrtf((float)(v + 1));
    sm[t] = v;
    __syncthreads();
    for (int off = 1; off < 256; off <<= 1) {
        int add = (t >= off) ? sm[t - off] : 0;
        __syncthreads();
        sm[t] += add;
        __syncthreads();
    }
    if (i < N) row_ptr[i] = sm[t] - v;  // block-local exclusive
    if (t == 255) partials[blockIdx.x] = sm[255];
}

__global__ __launch_bounds__(256) void scan_partials_kernel(int* partials, int NB) {
    __shared__ int sm[256];
    int t = threadIdx.x;
    int v = (t < NB) ? partials[t] : 0;
    sm[t] = v;
    __syncthreads();
    for (int off = 1; off < 256; off <<= 1) {
        int add = (t >= off) ? sm[t - off] : 0;
        __syncthreads();
        sm[t] += add;
        __syncthreads();
    }
    if (t < NB) partials[t] = sm[t] - v;  // exclusive
}

// fill: row_ptr[d] is a block-local cursor; global pos = cursor + partials[d>>8].
// Record packs {fp16(dinv[s]*dinv[d]) << 16 | src}.  (N < 65536)
__global__ __launch_bounds__(256) void fill_kernel(const int* __restrict__ src,
                                                   const int* __restrict__ dst,
                                                   const float* __restrict__ dinv,
                                                   int* row_ptr,
                                                   const int* __restrict__ partials,
                                                   unsigned int* edges, int E) {
    int i = blockIdx.x * 256 + threadIdx.x;
    if (i < E) {
        int d = dst[i];
        int s = src[i];
        int pos = atomicAdd(&row_ptr[d], 1) + partials[d >> 8];
        float w = dinv[s] * dinv[d];
        unsigned int rec = ((unsigned int)__half_as_ushort(__float2half_rn(w)) << 16)
                         | (unsigned int)s;
        edges[pos] = rec;
    }
}

// ---------- W1 -> W1^T fp16 ----------
__global__ __launch_bounds__(256) void wt_prep_kernel(const float* __restrict__ W1,
                                                      _Float16* __restrict__ WT) {
    int idx = blockIdx.x * 256 + threadIdx.x;
    if (idx < 128 * 128) {
        int k = idx >> 7, j = idx & 127;
        WT[j * 128 + k] = (_Float16)W1[idx];
    }
}

// ---------- GEMM1 (MFMA): h1 = X @ W1, f16 out ----------
__global__ __launch_bounds__(256) void gemm1_mfma_kernel(const float* __restrict__ X,
                                                         const _Float16* __restrict__ WT,
                                                         __half* __restrict__ H, int N) {
    __shared__ _Float16 As[64][136];

    int row0 = blockIdx.x * 64;
    {
        int r = threadIdx.x >> 2;
        int c0 = (threadIdx.x & 3) * 32;
        int row = row0 + r;
        if (row < N) {
            const float4* srcp = (const float4*)(X + (size_t)row * 128 + c0);
#pragma unroll
            for (int i = 0; i < 8; ++i) {
                float4 v = srcp[i];
                f16x4 h = {(_Float16)v.x, (_Float16)v.y, (_Float16)v.z, (_Float16)v.w};
                *(f16x4*)&As[r][c0 + 4 * i] = h;
            }
        } else {
            f16x4 z = {};
#pragma unroll
            for (int i = 0; i < 8; ++i) *(f16x4*)&As[r][c0 + 4 * i] = z;
        }
    }
    __syncthreads();

    int wave = threadIdx.x >> 6;
    int lane = threadIdx.x & 63;
    int l15 = lane & 15;
    int k0 = (lane >> 4) * 8;
    int arow = wave * 16 + l15;

    f32x4 acc[8] = {};
#pragma unroll
    for (int ks = 0; ks < 4; ++ks) {
        f16x8 a = *(const f16x8*)&As[arow][ks * 32 + k0];
#pragma unroll
        for (int t = 0; t < 8; ++t) {
            f16x8 b = *(const f16x8*)(WT + (size_t)(t * 16 + l15) * 128 + ks * 32 + k0);
            acc[t] = __builtin_amdgcn_mfma_f32_16x16x32_f16(a, b, acc[t], 0, 0, 0);
        }
    }

    int rbase = row0 + wave * 16 + (lane >> 4) * 4;
#pragma unroll
    for (int t = 0; t < 8; ++t) {
#pragma unroll
        for (int r = 0; r < 4; ++r) {
            int row = rbase + r;
            if (row < N) H[(size_t)row * 128 + t * 16 + l15] = __float2half(acc[t][r]);
        }
    }
}

// ---------- gather1 fused: agg(h1) -> +b1 -> LN -> ReLU -> @W2 -> h3 (fp16) ----------
__global__ __launch_bounds__(256) void gather1_fused_kernel(
    const __half* __restrict__ h1, const float* __restrict__ dinv,
    const int* __restrict__ row_ptr, const int* __restrict__ counts,
    const int* __restrict__ partials, const unsigned int* __restrict__ edges,
    const float* __restrict__ b1, const float* __restrict__ g1,
    const float* __restrict__ beta1, const float* __restrict__ W2,
    __half* __restrict__ h3, int N) {
    __shared__ float lds[4][K_DIM];
    int wave = threadIdx.x >> 6;
    int lane = threadIdx.x & 63;
    int node = blockIdx.x * 4 + wave;
    if (node >= N) return;

    float dd = dinv[node];
    float2 acc = __half22float2(((const __half2*)(h1 + (size_t)node * 128))[lane]);
    acc.x *= dd * dd; acc.y *= dd * dd;

    int end = row_ptr[node] + partials[node >> 8];
    int beg = end - counts[node];
    // wave-uniform bounds -> scalar record loads
    beg = __builtin_amdgcn_readfirstlane(beg);
    end = __builtin_amdgcn_readfirstlane(end);

    for (int e = beg; e < end; e += 8) {
        unsigned int rec[8];
#pragma unroll
        for (int i = 0; i < 8; ++i) rec[i] = edges[e + i];   // uniform addr (pad-safe)
        __half2 v[8];
#pragma unroll
        for (int i = 0; i < 8; ++i)
            v[i] = ((const __half2*)(h1 + (size_t)(rec[i] & 0xFFFFu) * 128))[lane];
#pragma unroll
        for (int i = 0; i < 8; ++i) {
            float w = (e + i < end)
                          ? __half2float(__ushort_as_half((unsigned short)(rec[i] >> 16)))
                          : 0.0f;
            float2 f = __half22float2(v[i]);
            acc.x = fmaf(f.x, w, acc.x);
            acc.y = fmaf(f.y, w, acc.y);
        }
    }

    // bias + LN + ReLU
    float2 bb = ((const float2*)b1)[lane];
    acc.x += bb.x; acc.y += bb.y;
    float s = acc.x + acc.y;
    for (int off = 32; off; off >>= 1) s += __shfl_xor(s, off);
    float mu = s * (1.0f / 128.0f);
    float dx = acc.x - mu, dy = acc.y - mu;
    float q = dx * dx + dy * dy;
    for (int off = 32; off; off >>= 1) q += __shfl_xor(q, off);
    float rstd = rsqrtf(q * (1.0f / 128.0f) + 1e-5f);
    float2 gg = ((const float2*)g1)[lane];
    float2 be = ((const float2*)beta1)[lane];
    float ox = fmaxf(fmaf(dx * rstd, gg.x, be.x), 0.0f);
    float oy = fmaxf(fmaf(dy * rstd, gg.y, be.y), 0.0f);

    // 128x64 matvec via LDS broadcast; lane owns output col = lane
    ((float2*)&lds[wave][0])[lane] = make_float2(ox, oy);
    float o = 0.0f;
#pragma unroll 8
    for (int k = 0; k < K_DIM; k += 4) {
        float4 vv = *(const float4*)&lds[wave][k];
        o = fmaf(vv.x, W2[(size_t)(k + 0) * 64 + lane], o);
        o = fmaf(vv.y, W2[(size_t)(k + 1) * 64 + lane], o);
        o = fmaf(vv.z, W2[(size_t)(k + 2) * 64 + lane], o);
        o = fmaf(vv.w, W2[(size_t)(k + 3) * 64 + lane], o);
    }
    h3[(size_t)node * 64 + lane] = __float2half(o);
}

// ---------- gather2 fused: agg(h3) -> +b2 -> LN -> ReLU -> L2 -> out ----------
__global__ __launch_bounds__(256) void gather2_fused_kernel(
    const __half* __restrict__ h3, const float* __restrict__ dinv,
    const int* __restrict__ row_ptr, const int* __restrict__ counts,
    const int* __restrict__ partials, const unsigned int* __restrict__ edges,
    const float* __restrict__ b2, const float* __restrict__ g2,
    const float* __restrict__ beta2, float* __restrict__ out, int N) {
    int wave = threadIdx.x >> 6;
    int lane = threadIdx.x & 63;
    int node = blockIdx.x * 4 + wave;
    if (node >= N) return;

    float dd = dinv[node];
    float acc = __half2float(h3[(size_t)node * 64 + lane]) * dd * dd;

    int end = row_ptr[node] + partials[node >> 8];
    int beg = end - counts[node];
    beg = __builtin_amdgcn_readfirstlane(beg);
    end = __builtin_amdgcn_readfirstlane(end);

    for (int e = beg; e < end; e += 8) {
        unsigned int rec[8];
#pragma unroll
        for (int i = 0; i < 8; ++i) rec[i] = edges[e + i];
        __half v[8];
#pragma unroll
        for (int i = 0; i < 8; ++i)
            v[i] = h3[(size_t)(rec[i] & 0xFFFFu) * 64 + lane];
#pragma unroll
        for (int i = 0; i < 8; ++i) {
            float w = (e + i < end)
                          ? __half2float(__ushort_as_half((unsigned short)(rec[i] >> 16)))
                          : 0.0f;
            acc = fmaf(__half2float(v[i]), w, acc);
        }
    }

    float v = acc + b2[lane];
    float s = v;
    for (int off = 32; off; off >>= 1) s += __shfl_xor(s, off);
    float mu = s * (1.0f / 64.0f);
    float d = v - mu;
    float q = d * d;
    for (int off = 32; off; off >>= 1) q += __shfl_xor(q, off);
    float rstd = rsqrtf(q * (1.0f / 64.0f) + 1e-5f);
    float o = fmaxf(fmaf(d * rstd, g2[lane], beta2[lane]), 0.0f);
    float q2 = o * o;
    for (int off = 32; off; off >>= 1) q2 += __shfl_xor(q2, off);
    float nrm = sqrtf(q2);
    out[(size_t)node * 64 + lane] = o / fmaxf(nrm, 1e-12f);
}

extern "C" void kernel_launch(void* const* d_in, const int* in_sizes, int n_in,
                              void* d_out, int out_size, void* d_ws, size_t ws_size,
                              hipStream_t stream) {
    const float* x     = (const float*)d_in[0];
    const int*   ei    = (const int*)d_in[1];
    const float* W1    = (const float*)d_in[2];
    const float* b1    = (const float*)d_in[3];
    const float* g1    = (const float*)d_in[4];
    const float* beta1 = (const float*)d_in[5];
    const float* W2    = (const float*)d_in[6];
    const float* b2    = (const float*)d_in[7];
    const float* g2    = (const float*)d_in[8];
    const float* beta2 = (const float*)d_in[9];

    const int N = in_sizes[0] / 128;
    const int E = in_sizes[1] / 2;
    const int* src = ei;       // edge_index[0]
    const int* dst = ei + E;   // edge_index[1]
    float* out = (float*)d_out;

    // Workspace (~23 MB)
    char* p = (char*)d_ws;
    auto alloc = [&](size_t bytes) { char* r = p; p += (bytes + 255) & ~(size_t)255; return r; };
    int*          counts   = (int*)alloc((size_t)N * 4);
    int*          row_ptr  = (int*)alloc((size_t)N * 4);
    int*          partials = (int*)alloc(256 * 4);
    float*        dinv     = (float*)alloc((size_t)N * 4);
    unsigned int* edges    = (unsigned int*)alloc(((size_t)E + 64) * 4);  // +pad
    _Float16*     WT       = (_Float16*)alloc(128 * 128 * 2);
    __half*       h1       = (__half*)alloc((size_t)N * 128 * 2);
    __half*       h3       = (__half*)alloc((size_t)N * 64 * 2);

    const int nb_nodes = (N + 255) / 256;
    const int nb_edges = (E + 255) / 256;
    const int nb_wave_nodes = (N + 3) / 4;

    // CSR build + dinv + packed 4-byte edge records (+ zeroed pad)
    hipMemsetAsync(counts, 0, (size_t)N * 4, stream);
    hipMemsetAsync(edges + E, 0, 64 * 4, stream);
    hist_kernel<<<nb_edges, 256, 0, stream>>>(dst, counts, E);
    scan_block_kernel<<<nb_nodes, 256, 0, stream>>>(counts, row_ptr, partials, dinv, N);
    scan_partials_kernel<<<1, 256, 0, stream>>>(partials, nb_nodes);
    fill_kernel<<<nb_edges, 256, 0, stream>>>(src, dst, dinv, row_ptr, partials, edges, E);

    // layer 1 GEMM (MFMA, f16 out)
    wt_prep_kernel<<<64, 256, 0, stream>>>(W1, WT);
    gemm1_mfma_kernel<<<(N + 63) / 64, 256, 0, stream>>>(x, WT, h1, N);

    // layer 1 aggregate + LN + ReLU + layer 2 GEMM (fused)
    gather1_fused_kernel<<<nb_wave_nodes, 256, 0, stream>>>(
        h1, dinv, row_ptr, counts, partials, edges, b1, g1, beta1, W2, h3, N);

    // layer 2 aggregate + LN + ReLU + L2 (fused)
    gather2_fused_kernel<<<nb_wave_nodes, 256, 0, stream>>>(
        h3, dinv, row_ptr, counts, partials, edges, b2, g2, beta2, out, N);
}